// Round 1
// baseline (67.820 us; speedup 1.0000x reference)
//
#include <hip/hip_runtime.h>

// Sliding-window attention, window=127 (+-63), B=4 L=4096 NH=16 H=64, fp32 in/out.
// Round-1 design:
//  - memory-bound: ideal HBM = 256MB -> ~41us floor @6.3TB/s. f16 MFMA keeps compute ~5x under that.
//  - block = (b, head, 128-query chunk); 4 waves x 32 queries; each wave does its 5 of 8 32-key tiles.
//  - swapped QK^T: mfma(K,Q) -> S^T, query = lane col -> per-lane softmax denominator, no max-subtract
//    (log2e folded into q scale, exp2 directly; scores bounded so no overflow risk).
//  - P fragments rebuilt in-register (f16 pack + 4 cross-half exchanges) -> PV A-operand, no LDS round trip.
//  - V staged transposed in LDS [64][264] f16 (b128 reads, padded stride); K,Q direct global->reg.
//  - epilogue: O -> LDS (aliased over V after barrier) -> normalized coalesced float4 stores.
//  - XCD swizzle: consecutive chunks of one head land on the same XCD (K/V window overlap -> L2 hits).

typedef _Float16 f16;
typedef _Float16 f16x2  __attribute__((ext_vector_type(2)));
typedef _Float16 f16x8  __attribute__((ext_vector_type(8)));
typedef float    f32x16 __attribute__((ext_vector_type(16)));
typedef int      int4v  __attribute__((ext_vector_type(4)));

constexpr int NB = 4, L = 4096, NH = 16, H = 64;
constexpr int CQ = 128, NC = L / CQ, KW = 256, WR = 63;
constexpr int RS  = NH * H;   // seq-row stride in floats
constexpr int VST = 264;      // V_lds row stride (f16): 528B -> 4-bank shift per row, 16B aligned
constexpr int OST = 68;       // O_lds row stride (f32)

#define DEV static __device__ __forceinline__

DEV int iclamp(int x, int lo, int hi) { return x < lo ? lo : (x > hi ? hi : x); }

DEV float fexp2(float x) {
#if __has_builtin(__builtin_amdgcn_exp2f)
    return __builtin_amdgcn_exp2f(x);
#else
    return exp2f(x);
#endif
}

DEV int packh2(float a, float b) {
    f16x2 p; p.x = (f16)a; p.y = (f16)b;   // RNE casts
    return __builtin_bit_cast(int, p);
}

// After call: new_a[l<32]=a[l], new_a[l>=32]=b[l^32]; new_b[l<32]=a[l^32], new_b[l>=32]=b[l].
// (shfl_xor version this round; permlane32_swap candidate for a later A/B)
DEV void swap_halves(int& a, int& b, int hi) {
    int pa = __shfl_xor(a, 32, 64);
    int pb = __shfl_xor(b, 32, 64);
    int na = hi ? pb : a;
    int nb = hi ? b  : pa;
    a = na; b = nb;
}

__global__ __launch_bounds__(256, 3)
void wattn_kernel(const float* __restrict__ q_, const float* __restrict__ k_,
                  const float* __restrict__ v_, float* __restrict__ o_)
{
    __shared__ alignas(16) char smem[CQ * OST * 4 + CQ * 4];   // 35328B; V_T (33792B) aliases low part
    f16*   V_lds = (f16*)smem;                      // [H][VST] during compute
    float* O_lds = (float*)smem;                    // [CQ][OST] after barrier
    float* D_lds = (float*)(smem + CQ * OST * 4);   // [CQ] reciprocal denominators

    // XCD-aware swizzle: 2048 blocks, 8 XCDs, 2048%8==0 -> bijective
    const int bid = (int)blockIdx.x;
    const int wid = (bid & 7) * ((NB * NH * NC) / 8) + (bid >> 3);
    const int c = wid & (NC - 1);
    const int n = (wid >> 5) & (NH - 1);
    const int b = wid >> 9;

    const int t    = (int)threadIdx.x;
    const int lane = t & 63;
    const int wq   = t >> 6;       // wave id = 32-query tile
    const int lq   = lane & 31;
    const int hi   = lane >> 5;

    const int kg0 = c * CQ - WR;                       // global seq row of window key j=0
    const size_t bn = ((size_t)b * L * NH + n) * H;    // element offset of (b,0,n,0)

    // ---- stage V transposed into LDS (coalesced float4 loads, f16x2 pair writes) ----
    #pragma unroll
    for (int p = 0; p < 8; ++p) {
        int idx = p * 256 + t;
        int r0  = (idx >> 4) << 1;       // even key row in window
        int h4  = (idx & 15) << 2;
        int kr0 = iclamp(kg0 + r0,     0, L - 1);
        int kr1 = iclamp(kg0 + r0 + 1, 0, L - 1);
        float4 v0 = *(const float4*)(v_ + bn + (size_t)kr0 * RS + h4);
        float4 v1 = *(const float4*)(v_ + bn + (size_t)kr1 * RS + h4);
        *(f16x2*)(V_lds + (h4 + 0) * VST + r0) = (f16x2){(f16)v0.x, (f16)v1.x};
        *(f16x2*)(V_lds + (h4 + 1) * VST + r0) = (f16x2){(f16)v0.y, (f16)v1.y};
        *(f16x2*)(V_lds + (h4 + 2) * VST + r0) = (f16x2){(f16)v0.z, (f16)v1.z};
        *(f16x2*)(V_lds + (h4 + 3) * VST + r0) = (f16x2){(f16)v0.w, (f16)v1.w};
    }

    // ---- Q fragments (B-operand: lane holds Q[q=lq][h = 16*tq + 8*hi + j]) ----
    const int iq = wq * 32 + lq;
    const float qs = 0.125f * 1.44269504088896f;   // h^-0.5 * log2(e)
    const float* qrow = q_ + bn + (size_t)(c * CQ + iq) * RS + hi * 8;
    f16x8 qf[4];
    #pragma unroll
    for (int tq = 0; tq < 4; ++tq) {
        float4 a  = *(const float4*)(qrow + tq * 16);
        float4 b2 = *(const float4*)(qrow + tq * 16 + 4);
        qf[tq] = (f16x8){(f16)(a.x * qs),  (f16)(a.y * qs),  (f16)(a.z * qs),  (f16)(a.w * qs),
                         (f16)(b2.x * qs), (f16)(b2.y * qs), (f16)(b2.z * qs), (f16)(b2.w * qs)};
    }

    // window mask bounds: allowed local keys j with j-iq in [0,126] and kg0+j in [0,L)
    const int jlo = (c == 0) ? WR : 0;
    const int jhi = (KW < L - kg0) ? KW : (L - kg0);
    const int lo  = (iq > jlo) ? iq : jlo;
    const int hb  = (iq + 126 < jhi - 1) ? (iq + 126) : (jhi - 1);
    const unsigned span = (unsigned)(hb - lo);

    f32x16 o0, o1;
    #pragma unroll
    for (int r = 0; r < 16; ++r) { o0[r] = 0.f; o1[r] = 0.f; }
    float dsum = 0.f;

    __syncthreads();

    for (int kt = wq; kt < wq + 5; ++kt) {
        // ---- S^T tile = K_tile(32k x 64h) . Q^T : D rows = keys, cols = queries ----
        f32x16 s;
        #pragma unroll
        for (int r = 0; r < 16; ++r) s[r] = 0.f;
        const int kg = iclamp(kg0 + kt * 32 + lq, 0, L - 1);   // clamped; OOB keys masked below
        const float* krow = k_ + bn + (size_t)kg * RS + hi * 8;
        #pragma unroll
        for (int tq = 0; tq < 4; ++tq) {
            float4 ka = *(const float4*)(krow + tq * 16);
            float4 kb = *(const float4*)(krow + tq * 16 + 4);
            f16x8 af = (f16x8){(f16)ka.x, (f16)ka.y, (f16)ka.z, (f16)ka.w,
                               (f16)kb.x, (f16)kb.y, (f16)kb.z, (f16)kb.w};
            s = __builtin_amdgcn_mfma_f32_32x32x16_f16(af, qf[tq], s, 0, 0, 0);
        }
        // ---- mask + exp2 + denominator (per-lane: q = lq) ----
        const int jb = kt * 32 + 4 * hi;
        float pe[16];
        #pragma unroll
        for (int r = 0; r < 16; ++r) {
            int j = jb + (r & 3) + ((r >> 2) << 3);      // D-row -> local key index
            float e = fexp2(s[r]);
            e = ((unsigned)(j - lo) <= span) ? e : 0.f;
            dsum += e;
            pe[r] = e;
        }
        // ---- P fragments: pack to f16 pairs, exchange across lane halves -> A-operand ----
        int d0 = packh2(pe[0],  pe[1]),  d1 = packh2(pe[2],  pe[3]);
        int d2 = packh2(pe[4],  pe[5]),  d3 = packh2(pe[6],  pe[7]);
        int d4 = packh2(pe[8],  pe[9]),  d5 = packh2(pe[10], pe[11]);
        int d6 = packh2(pe[12], pe[13]), d7 = packh2(pe[14], pe[15]);
        swap_halves(d0, d2, hi); swap_halves(d1, d3, hi);
        swap_halves(d4, d6, hi); swap_halves(d5, d7, hi);
        f16x8 pa0 = __builtin_bit_cast(f16x8, (int4v){d0, d1, d2, d3});   // keys kt*32 + 0..15
        f16x8 pa1 = __builtin_bit_cast(f16x8, (int4v){d4, d5, d6, d7});   // keys kt*32 + 16..31
        // ---- PV: O[32q][64h] += P . V, B-operand from transposed V in LDS ----
        const int kb0 = kt * 32 + hi * 8;
        const f16* vr0 = V_lds + lq * VST + kb0;          // h = lq
        const f16* vr1 = V_lds + (32 + lq) * VST + kb0;   // h = 32 + lq
        o0 = __builtin_amdgcn_mfma_f32_32x32x16_f16(pa0, *(const f16x8*)(vr0),      o0, 0, 0, 0);
        o0 = __builtin_amdgcn_mfma_f32_32x32x16_f16(pa1, *(const f16x8*)(vr0 + 16), o0, 0, 0, 0);
        o1 = __builtin_amdgcn_mfma_f32_32x32x16_f16(pa0, *(const f16x8*)(vr1),      o1, 0, 0, 0);
        o1 = __builtin_amdgcn_mfma_f32_32x32x16_f16(pa1, *(const f16x8*)(vr1 + 16), o1, 0, 0, 0);
    }

    __syncthreads();   // all waves done reading V_lds; reuse LDS for O staging

    // O fragments -> LDS (D layout: row q = (r&3)+8*(r>>2)+4*hi, col h = lq / 32+lq)
    #pragma unroll
    for (int r = 0; r < 16; ++r) {
        int irow = wq * 32 + (r & 3) + ((r >> 2) << 3) + 4 * hi;
        O_lds[irow * OST + lq]      = o0[r];
        O_lds[irow * OST + 32 + lq] = o1[r];
    }
    float dtot = dsum + __shfl_xor(dsum, 32, 64);
    if (lane < 32) D_lds[wq * 32 + lq] = 1.0f / dtot;
    __syncthreads();

    // normalized, coalesced float4 stores: out[b][c*128+irow][n][h]
    const size_t ob = ((size_t)b * L + (size_t)c * CQ) * RS + (size_t)n * H;
    #pragma unroll
    for (int it = 0; it < 8; ++it) {
        int flat = it * 256 + t;
        int irow = flat >> 4;
        int h4   = (flat & 15) << 2;
        float rd = D_lds[irow];
        const float* src = O_lds + irow * OST + h4;
        float4 val;
        val.x = src[0] * rd; val.y = src[1] * rd;
        val.z = src[2] * rd; val.w = src[3] * rd;
        *(float4*)(o_ + ob + (size_t)irow * RS + h4) = val;
    }
}

extern "C" void kernel_launch(void* const* d_in, const int* in_sizes, int n_in,
                              void* d_out, int out_size, void* d_ws, size_t ws_size,
                              hipStream_t stream) {
    const float* q = (const float*)d_in[0];
    const float* k = (const float*)d_in[1];
    const float* v = (const float*)d_in[2];
    float* o = (float*)d_out;
    (void)in_sizes; (void)n_in; (void)out_size; (void)d_ws; (void)ws_size;
    wattn_kernel<<<dim3(NB * NH * NC), dim3(256), 0, stream>>>(q, k, v, o);
}